// Round 8
// baseline (1214.138 us; speedup 1.0000x reference)
//
#include <hip/hip_runtime.h>
#include <math.h>

#define NV 128         // vector length (complex) = 8*8*2
#define NTRI 8256      // lower-tri entries of 128x128
#define NPAD8R 8960    // 8-padded triangle (8704) + 2-complex skew per row (256)
#define KAP 0.276f
#define MAXIT 20
#define TPB 512        // 8 waves; LDS ~79 KB -> 2 blocks/CU

__device__ __forceinline__ float2 f2(float x, float y){ return make_float2(x, y); }
__device__ __forceinline__ float2 cadd(float2 a, float2 b){ return make_float2(a.x+b.x, a.y+b.y); }
__device__ __forceinline__ float2 csub(float2 a, float2 b){ return make_float2(a.x-b.x, a.y-b.y); }
__device__ __forceinline__ float2 cmul(float2 a, float2 b){ return make_float2(a.x*b.x - a.y*b.y, a.x*b.y + a.y*b.x); }
__device__ __forceinline__ float2 cmulc(float2 a, float2 b){ // conj(a)*b
  return make_float2(a.x*b.x + a.y*b.y, a.x*b.y - a.y*b.x); }
__device__ __forceinline__ float2 cmac(float2 acc, float2 a, float2 b){ // acc += a*b
  acc.x = fmaf(a.x, b.x, fmaf(-a.y, b.y, acc.x));
  acc.y = fmaf(a.x, b.y, fmaf( a.y, b.x, acc.y));
  return acc; }
__device__ __forceinline__ float2 cmacc(float2 acc, float2 a, float2 b){ // acc += conj(a)*b
  acc.x = fmaf(a.x, b.x, fmaf( a.y, b.y, acc.x));
  acc.y = fmaf(a.x, b.y, fmaf(-a.y, b.x, acc.y));
  return acc; }
__device__ __forceinline__ float2 cdiv(float2 n, float2 d){
  float s = 1.0f / fmaf(d.x, d.x, d.y*d.y);
  return make_float2((n.x*d.x + n.y*d.y)*s, (n.y*d.x - n.x*d.y)*s); }

// Row r start: 8-padded triangle offset + 2-complex-per-row skew (bank spread).
__device__ __forceinline__ int soff8(int r){
  const int a = r >> 3;
  return ((((a + 1) * ((a << 2) + (r & 7)))) << 3) + (r << 1);
}
// storage swizzle key for row r: XOR on complex-index bits 1-2
__device__ __forceinline__ int skey(int r){ return ((r >> 1) & 3) << 1; }

// sum over the 8 lanes {c=0..3} x {h=0,1} of a pair group (xor 1,2,32)
__device__ __forceinline__ float2 red8(float2 v){
  v.x += __shfl_xor(v.x, 1);  v.y += __shfl_xor(v.y, 1);
  v.x += __shfl_xor(v.x, 2);  v.y += __shfl_xor(v.y, 2);
  v.x += __shfl_xor(v.x, 32); v.y += __shfl_xor(v.y, 32);
  return v;
}

// Wilson-Dirac hop. EF = coefficient sign of G on the FORWARD hop:
//   D : fwd (I - G), bwd (I + G) -> EF=-1 ; Ddag : EF=+1
// Register-return variant: no store, no barrier (caller guards t<NV).
template<int EF>
__device__ __forceinline__ float2 dirac_reg(const float2* __restrict__ U,
                                            const float2* __restrict__ vin, int t)
{
  const int s = t & 1, site = t >> 1;
  const int yi = site & 7, xi = site >> 3;
  const int xp = (xi+1)&7, xm = (xi-1)&7, yp = (yi+1)&7, ym = (yi-1)&7;
  float2 acc;
  {
    const int bf = (xp<<4) + (yi<<1);
    float2 fs = vin[bf + s], fo = vin[bf + (s^1)];
    float2 cf = (EF > 0) ? cadd(fs, fo) : csub(fs, fo);
    acc = cmul(U[(xi<<3)+yi], cf);
    const int bb = (xm<<4) + (yi<<1);
    float2 bs = vin[bb + s], bo = vin[bb + (s^1)];
    float2 cb = (EF > 0) ? csub(bs, bo) : cadd(bs, bo);
    acc = cadd(acc, cmulc(U[(xm<<3)+yi], cb));
  }
  {
    const float tg = s ? 1.0f : -1.0f;
    const float gf = (float)EF * tg;
    const int bf = (xi<<4) + (yp<<1);
    float2 fs = vin[bf + s], fo = vin[bf + (s^1)];
    float2 cf = make_float2(fmaf(-gf, fo.y, fs.x), fmaf(gf, fo.x, fs.y));
    acc = cadd(acc, cmul(U[64 + (xi<<3)+yi], cf));
    const float gb = -gf;
    const int bb = (xi<<4) + (ym<<1);
    float2 bs = vin[bb + s], bo = vin[bb + (s^1)];
    float2 cb = make_float2(fmaf(-gb, bo.y, bs.x), fmaf(gb, bo.x, bs.y));
    acc = cadd(acc, cmulc(U[64 + (xi<<3)+ym], cb));
  }
  float2 v0 = vin[t];
  return make_float2(fmaf(-KAP, acc.x, v0.x), fmaf(-KAP, acc.y, v0.y));
}

// Store variant (with trailing barrier), used when the result feeds neighbor reads.
template<int EF>
__device__ __forceinline__ void dirac(const float2* __restrict__ U,
                                      const float2* __restrict__ vin,
                                      float2* __restrict__ vout, int t)
{
  if (t < NV) vout[t] = dirac_reg<EF>(U, vin, t);
  __syncthreads();
}

// One-time gather of this lane's pass-1 L operands into registers.
// Slot i mirrors pass 1's slab selection exactly; slot 8 = epilogue slab
// (rhi slab 7-w; consumed only by h=0 lanes but loaded by all — valid addr).
__device__ __forceinline__ void load_P1(const float2* __restrict__ Lc2,
                                        float4 (&P1)[9], int w, int lane)
{
  const int c = lane & 3, g = lane >> 2, q = g & 7, h = g >> 3, c2 = c << 1;
  const int rlo = (w << 3) + q, rhi = 127 - rlo;
  const int bLo = soff8(rlo), bHi = soff8(rhi);
  #pragma unroll
  for (int i = 0; i < 8; ++i) {
    const int k    = h ? (8 - w + i) : ((i <= w) ? i : (i - w - 1));
    const int base = (!h && (i <= w)) ? bLo : bHi;
    P1[i] = *(const float4*)&Lc2[base + (k << 3) + c2];
  }
  P1[8] = *(const float4*)&Lc2[bHi + ((7 - w) << 3) + c2];
}

// z = L^H (L v). Pass 1 uses register-resident L (P1); only v comes from LDS.
// Pass 2 unchanged (round-3 verified addressing). Fused dot(vin,z) into pass 2.
__device__ __forceinline__ void precond(const float2* __restrict__ Lc2,
                                        const float4 (&P1)[9],
                                        const float2* __restrict__ vin,
                                        float2* __restrict__ wvv,
                                        float2* __restrict__ vout,
                                        float2* __restrict__ scal,
                                        int w, int lane)
{
  const int c  = lane & 3;
  const int g  = lane >> 2;
  const int q  = g & 7;
  const int h  = g >> 3;
  const int c2 = c << 1;
  const int rlo = (w << 3) + q;        // 0..63
  const int rhi = 127 - rlo;           // 64..127
  const int keyLo = skey(rlo);
  const int keyHi = skey(rhi);

  // ---- pass 1: w_r = sum_{j<=r} L[r][j] v[j]  (L from registers) ----
  {
    float2 a0 = f2(0.f, 0.f), a1 = f2(0.f, 0.f);
    #pragma unroll
    for (int i = 0; i < 8; ++i) {
      const int k    = h ? (8 - w + i) : ((i <= w) ? i : (i - w - 1));
      const int keyR = (!h && (i <= w)) ? keyLo : keyHi;
      const float4 vp = *(const float4*)&vin[(k << 3) + (c2 ^ keyR)];
      const float4 Lp = P1[i];
      if (i <= w) a0 = cmac(cmac(a0, f2(Lp.x,Lp.y), f2(vp.x,vp.y)), f2(Lp.z,Lp.w), f2(vp.z,vp.w));
      else        a1 = cmac(cmac(a1, f2(Lp.x,Lp.y), f2(vp.x,vp.y)), f2(Lp.z,Lp.w), f2(vp.z,vp.w));
    }
    if (!h) {  // epilogue slab 9 of group A: rhi slab 7-w
      const float4 vp = *(const float4*)&vin[((7 - w) << 3) + (c2 ^ keyHi)];
      const float4 Lp = P1[8];
      a1 = cmac(cmac(a1, f2(Lp.x,Lp.y), f2(vp.x,vp.y)), f2(Lp.z,Lp.w), f2(vp.z,vp.w));
    }
    float2 vLo = h ? f2(0.f, 0.f) : a0;
    float2 vHi = h ? cadd(a0, a1) : a1;
    vLo = red8(vLo);
    vHi = red8(vHi);
    if (c == 0) wvv[h ? rhi : rlo] = h ? vHi : vLo;
  }
  __syncthreads();

  // ---- pass 2: z_j = sum_{i>=j} conj(L[i][j]) w[i]  (+ fused dot(vin,z)) ----
  {
    const int key2 = c2;
    float2 a0 = f2(0.f, 0.f), a1 = f2(0.f, 0.f);
    #pragma unroll
    for (int i = 0; i < 8; ++i) {
      int k, j;
      if (i <= w) {
        k = h ? (8 + i) : (15 - w + i);
        j = h ? rlo : rhi;
      } else {
        k = h ? (8 + i) : (i - 1);
        j = rlo;
      }
      const int u    = (k + 1) << 3;
      const int off0 = u * ((k << 2) + c2) + (k << 4) + (c2 << 1) + (j ^ key2);
      const int off1 = off0 + u + 2;
      const int i0   = (k << 3) + c2;
      const float2 La = Lc2[off0];
      const float2 Lb = Lc2[off1];
      const float4 wp = *(const float4*)&wvv[i0];
      if (i <= w) a0 = cmacc(cmacc(a0, La, f2(wp.x,wp.y)), Lb, f2(wp.z,wp.w));
      else        a1 = cmacc(cmacc(a1, La, f2(wp.x,wp.y)), Lb, f2(wp.z,wp.w));
    }
    if (!h) {  // epilogue slab 9 of group A: jlo slab 7 (rows 56+c2, 57+c2)
      const int o0 = (64 * (28 + c2)) + 112 + (c2 << 1) + (rlo ^ key2);
      const float2 La = Lc2[o0];
      const float2 Lb = Lc2[o0 + 66];
      const float4 wp = *(const float4*)&wvv[56 + c2];
      a1 = cmacc(cmacc(a1, La, f2(wp.x,wp.y)), Lb, f2(wp.z,wp.w));
    }
    float2 vJhi = h ? f2(0.f, 0.f) : a0;
    float2 vJlo = h ? cadd(a0, a1) : a1;
    vJhi = red8(vJhi);
    vJlo = red8(vJlo);
    // fused dot(vin, z): c0 lane holds z_j; partial = conj(r_j) z_j
    float2 dotp = f2(0.f, 0.f);
    if (c == 0) {
      const int jw = h ? rlo : rhi;
      const float2 zj = h ? vJlo : vJhi;
      vout[jw] = zj;
      dotp = cmacc(f2(0.f, 0.f), vin[jw], zj);
    }
    #pragma unroll
    for (int off = 32; off >= 4; off >>= 1) {
      dotp.x += __shfl_down(dotp.x, off, 64);
      dotp.y += __shfl_down(dotp.y, off, 64);
    }
    if (lane == 0) scal[w] = dotp;
  }
  __syncthreads();                                   // publishes zv + scal[0..7]
}

extern "C" __global__ void __launch_bounds__(TPB, 4)
cg_loss_kernel(const float* __restrict__ nre, const float* __restrict__ nim,
               const float* __restrict__ theta, const float* __restrict__ bin,
               float* __restrict__ out, float invB)
{
  __shared__ __align__(16) float2 Lc2[NPAD8R];      // 71680 B skewed+swizzled triangle
  __shared__ __align__(16) float2 Uc[128];
  __shared__ __align__(16) float2 bv[NV], rv[NV], pv[NV];
  __shared__ __align__(16) float2 zv[NV], tv[NV], wv[NV];
  __shared__ float2 scal[12];
  // total LDS = 71680 + 1024 + 6144 + 96 = 78944 B -> 2 blocks/CU

  const int t = threadIdx.x;
  const long long b = blockIdx.x;
  const int w = t >> 6, lane = t & 63;

  // ---- zero the padded triangle (pads/gaps must read as 0), init ----
  for (int p = t; p < NPAD8R; p += TPB) Lc2[p] = make_float2(0.f, 0.f);
  float2 xr = f2(0.f, 0.f), rr = f2(0.f, 0.f), pr = f2(0.f, 0.f), rz = f2(1.f, 0.f);
  if (t < NV) {
    float th = theta[b * 128 + t];
    float sn, cs;
    sincosf(th, &sn, &cs);
    Uc[t] = make_float2(cs, sn);                    // exp(i*theta)
    float bb = bin[b * 128 + t];
    bv[t] = make_float2(bb, 0.f);
    rr = make_float2(bb, 0.f);                      // r = b - A(0)
    rv[t] = rr;
  }
  __syncthreads();

  // ---- stage L into skewed+swizzled LDS; global reads fully coalesced ----
  {
    const float* nreb = nre + b * NTRI;
    const float* nimb = nim + b * NTRI;
    for (int p = t; p < NTRI; p += TPB) {
      float re = nreb[p], im = nimb[p];
      int r = (int)((sqrtf(8.f * (float)p + 1.f) - 1.f) * 0.5f + 1e-3f);
      int tr = (r * (r + 1)) >> 1;
      if (tr > p)               { tr -= r; --r; }        // tri(r-1) = tri(r) - r
      else if (tr + r + 1 <= p) { tr += r + 1; ++r; }
      Lc2[soff8(r) + ((p - tr) ^ skey(r))] = make_float2(re, im);
    }
  }
  __syncthreads();

  // ---- one-time: this lane's pass-1 L operands -> registers ----
  float4 P1[9];
  load_P1(Lc2, P1, w, lane);

  // ---- z = M r ; rz = dot(r,z) fused ; p = z ----
  precond(Lc2, P1, rv, wv, zv, scal, w, lane);
  if (t < NV) {
    rz = cadd(cadd(cadd(scal[0],scal[1]), cadd(scal[2],scal[3])),
              cadd(cadd(scal[4],scal[5]), cadd(scal[6],scal[7])));
    pr = zv[t];
    pv[t] = pr;
  }
  __syncthreads();

  #pragma unroll 1
  for (int it = 0; it < MAXIT - 1; ++it) {
    dirac<-1>(Uc, pv, tv, t);                       // t1 = D p (publishes tv)
    float2 ap = f2(0.f, 0.f);
    if (t < NV) {                                   // Ap = Ddag t1 (registers) + pAp dot
      ap = dirac_reg<+1>(Uc, tv, t);
      float2 v = cmacc(f2(0.f,0.f), pr, ap);
      #pragma unroll
      for (int off = 32; off > 0; off >>= 1) {
        v.x += __shfl_down(v.x, off, 64);
        v.y += __shfl_down(v.y, off, 64);
      }
      if ((t & 63) == 0) scal[8 + (t >> 6)] = v;
    }
    __syncthreads();                                // publishes pAp
    if (t < NV) {                                   // axpy entirely in registers
      float2 alpha = cdiv(rz, cadd(scal[8], scal[9]));
      xr = cmac(xr, alpha, pr);                     // x += alpha p
      rr = csub(rr, cmul(alpha, ap));               // r -= alpha Ap
      rv[t] = rr;
    }
    __syncthreads();                                // publishes rv
    precond(Lc2, P1, rv, wv, zv, scal, w, lane);    // z = M r ; scal[0..7] = rz2 partials
    if (t < NV) {
      float2 rz2 = cadd(cadd(cadd(scal[0],scal[1]), cadd(scal[2],scal[3])),
                        cadd(cadd(scal[4],scal[5]), cadd(scal[6],scal[7])));
      float2 beta = cdiv(rz2, rz);
      rz = rz2;
      pr = cmac(zv[t], beta, pr);                   // p = z + beta p
      pv[t] = pr;
    }
    __syncthreads();                                // publishes pv
  }

  // ---- final iteration: only x += alpha p matters ----
  dirac<-1>(Uc, pv, tv, t);
  {
    float2 ap = f2(0.f, 0.f);
    if (t < NV) {
      ap = dirac_reg<+1>(Uc, tv, t);
      float2 v = cmacc(f2(0.f,0.f), pr, ap);
      #pragma unroll
      for (int off = 32; off > 0; off >>= 1) {
        v.x += __shfl_down(v.x, off, 64);
        v.y += __shfl_down(v.y, off, 64);
      }
      if ((t & 63) == 0) scal[8 + (t >> 6)] = v;
    }
    __syncthreads();
    if (t < NV) {
      float2 alpha = cdiv(rz, cadd(scal[8], scal[9]));
      xr = cmac(xr, alpha, pr);
      rv[t] = xr;                                   // publish x (rv slot reused)
    }
    __syncthreads();
  }

  // ---- res = A x - b ; rn = ||res|| (fused into the second hop) ----
  dirac<-1>(Uc, rv, tv, t);                         // t1 = D x
  if (t < NV) {
    float2 ax = dirac_reg<+1>(Uc, tv, t);           // Ax = Ddag t1
    float2 d = csub(ax, bv[t]);
    float v = fmaf(d.x, d.x, d.y * d.y);
    #pragma unroll
    for (int off = 32; off > 0; off >>= 1) v += __shfl_down(v, off, 64);
    if ((t & 63) == 0) scal[10 + (t >> 6)].x = v;
  }
  __syncthreads();
  if (t == 0) {
    float rn = sqrtf(scal[10].x + scal[11].x);
    atomicAdd(out, rn * invB);
  }
}

extern "C" void kernel_launch(void* const* d_in, const int* in_sizes, int n_in,
                              void* d_out, int out_size, void* d_ws, size_t ws_size,
                              hipStream_t stream)
{
  const float* nre   = (const float*)d_in[0];
  const float* nim   = (const float*)d_in[1];
  const float* theta = (const float*)d_in[2];
  const float* bin   = (const float*)d_in[3];
  float* out = (float*)d_out;
  const int B = in_sizes[0] / NTRI;   // 2048

  hipMemsetAsync(out, 0, sizeof(float), stream);
  cg_loss_kernel<<<B, TPB, 0, stream>>>(nre, nim, theta, bin, out, 1.0f / (float)B);
}

// Round 9
// 1212.278 us; speedup vs baseline: 1.0015x; 1.0015x over previous
//
#include <hip/hip_runtime.h>
#include <math.h>

#define NV 128         // vector length (complex) = 8*8*2
#define NTRI 8256      // lower-tri entries of 128x128
#define NPAD8R 8960    // 8-padded triangle (8704) + 2-complex skew per row (256)
#define KAP 0.276f
#define MAXIT 20
#define TPB 512        // 8 waves; LDS ~79 KB -> 2 blocks/CU (4 waves/EU)

__device__ __forceinline__ float2 f2(float x, float y){ return make_float2(x, y); }
__device__ __forceinline__ float2 cadd(float2 a, float2 b){ return make_float2(a.x+b.x, a.y+b.y); }
__device__ __forceinline__ float2 csub(float2 a, float2 b){ return make_float2(a.x-b.x, a.y-b.y); }
__device__ __forceinline__ float2 cmul(float2 a, float2 b){ return make_float2(a.x*b.x - a.y*b.y, a.x*b.y + a.y*b.x); }
__device__ __forceinline__ float2 cmulc(float2 a, float2 b){ // conj(a)*b
  return make_float2(a.x*b.x + a.y*b.y, a.x*b.y - a.y*b.x); }
__device__ __forceinline__ float2 cmac(float2 acc, float2 a, float2 b){ // acc += a*b
  acc.x = fmaf(a.x, b.x, fmaf(-a.y, b.y, acc.x));
  acc.y = fmaf(a.x, b.y, fmaf( a.y, b.x, acc.y));
  return acc; }
__device__ __forceinline__ float2 cmacc(float2 acc, float2 a, float2 b){ // acc += conj(a)*b
  acc.x = fmaf(a.x, b.x, fmaf( a.y, b.y, acc.x));
  acc.y = fmaf(a.x, b.y, fmaf(-a.y, b.x, acc.y));
  return acc; }
__device__ __forceinline__ float2 cdiv(float2 n, float2 d){
  float s = 1.0f / fmaf(d.x, d.x, d.y*d.y);
  return make_float2((n.x*d.x + n.y*d.y)*s, (n.y*d.x - n.x*d.y)*s); }

// Row r start: 8-padded triangle offset + 2-complex-per-row skew (bank spread).
__device__ __forceinline__ int soff8(int r){
  const int a = r >> 3;
  return ((((a + 1) * ((a << 2) + (r & 7)))) << 3) + (r << 1);
}
// storage swizzle key for row r: XOR on complex-index bits 1-2
__device__ __forceinline__ int skey(int r){ return ((r >> 1) & 3) << 1; }

// sum over the 8 lanes {c=0..3} x {h=0,1} of a pair group (xor 1,2,32)
__device__ __forceinline__ float2 red8(float2 v){
  v.x += __shfl_xor(v.x, 1);  v.y += __shfl_xor(v.y, 1);
  v.x += __shfl_xor(v.x, 2);  v.y += __shfl_xor(v.y, 2);
  v.x += __shfl_xor(v.x, 32); v.y += __shfl_xor(v.y, 32);
  return v;
}

// Wilson-Dirac hop. EF = coefficient sign of G on the FORWARD hop:
//   D : fwd (I - G), bwd (I + G) -> EF=-1 ; Ddag : EF=+1
// Register-return variant: no store, no barrier (caller guards t<NV).
template<int EF>
__device__ __forceinline__ float2 dirac_reg(const float2* __restrict__ U,
                                            const float2* __restrict__ vin, int t)
{
  const int s = t & 1, site = t >> 1;
  const int yi = site & 7, xi = site >> 3;
  const int xp = (xi+1)&7, xm = (xi-1)&7, yp = (yi+1)&7, ym = (yi-1)&7;
  float2 acc;
  {
    const int bf = (xp<<4) + (yi<<1);
    float2 fs = vin[bf + s], fo = vin[bf + (s^1)];
    float2 cf = (EF > 0) ? cadd(fs, fo) : csub(fs, fo);
    acc = cmul(U[(xi<<3)+yi], cf);
    const int bb = (xm<<4) + (yi<<1);
    float2 bs = vin[bb + s], bo = vin[bb + (s^1)];
    float2 cb = (EF > 0) ? csub(bs, bo) : cadd(bs, bo);
    acc = cadd(acc, cmulc(U[(xm<<3)+yi], cb));
  }
  {
    const float tg = s ? 1.0f : -1.0f;
    const float gf = (float)EF * tg;
    const int bf = (xi<<4) + (yp<<1);
    float2 fs = vin[bf + s], fo = vin[bf + (s^1)];
    float2 cf = make_float2(fmaf(-gf, fo.y, fs.x), fmaf(gf, fo.x, fs.y));
    acc = cadd(acc, cmul(U[64 + (xi<<3)+yi], cf));
    const float gb = -gf;
    const int bb = (xi<<4) + (ym<<1);
    float2 bs = vin[bb + s], bo = vin[bb + (s^1)];
    float2 cb = make_float2(fmaf(-gb, bo.y, bs.x), fmaf(gb, bo.x, bs.y));
    acc = cadd(acc, cmulc(U[64 + (xi<<3)+ym], cb));
  }
  float2 v0 = vin[t];
  return make_float2(fmaf(-KAP, acc.x, v0.x), fmaf(-KAP, acc.y, v0.y));
}

// Store variant (with trailing barrier), used when the result feeds neighbor reads.
template<int EF>
__device__ __forceinline__ void dirac(const float2* __restrict__ U,
                                      const float2* __restrict__ vin,
                                      float2* __restrict__ vout, int t)
{
  if (t < NV) vout[t] = dirac_reg<EF>(U, vin, t);
  __syncthreads();
}

// One-time gather of this lane's pass-1 L operands into registers.
// Slot i mirrors pass 1's slab selection exactly; slot 8 = epilogue slab
// (rhi slab 7-w; consumed only by h=0 lanes but loaded by all — valid addr).
__device__ __forceinline__ void load_P1(const float2* __restrict__ Lc2,
                                        float4 (&P1)[9], int w, int lane)
{
  const int c = lane & 3, g = lane >> 2, q = g & 7, h = g >> 3, c2 = c << 1;
  const int rlo = (w << 3) + q, rhi = 127 - rlo;
  const int bLo = soff8(rlo), bHi = soff8(rhi);
  #pragma unroll
  for (int i = 0; i < 8; ++i) {
    const int k    = h ? (8 - w + i) : ((i <= w) ? i : (i - w - 1));
    const int base = (!h && (i <= w)) ? bLo : bHi;
    P1[i] = *(const float4*)&Lc2[base + (k << 3) + c2];
  }
  P1[8] = *(const float4*)&Lc2[bHi + ((7 - w) << 3) + c2];
}

// z = L^H (L v). Pass 1 uses register-resident L (P1); only v comes from LDS.
// Pass 2 unchanged (round-3 verified addressing). Fused dot(vin,z) into pass 2.
__device__ __forceinline__ void precond(const float2* __restrict__ Lc2,
                                        const float4 (&P1)[9],
                                        const float2* __restrict__ vin,
                                        float2* __restrict__ wvv,
                                        float2* __restrict__ vout,
                                        float2* __restrict__ scal,
                                        int w, int lane)
{
  const int c  = lane & 3;
  const int g  = lane >> 2;
  const int q  = g & 7;
  const int h  = g >> 3;
  const int c2 = c << 1;
  const int rlo = (w << 3) + q;        // 0..63
  const int rhi = 127 - rlo;           // 64..127
  const int keyLo = skey(rlo);
  const int keyHi = skey(rhi);

  // ---- pass 1: w_r = sum_{j<=r} L[r][j] v[j]  (L from registers) ----
  {
    float2 a0 = f2(0.f, 0.f), a1 = f2(0.f, 0.f);
    #pragma unroll
    for (int i = 0; i < 8; ++i) {
      const int k    = h ? (8 - w + i) : ((i <= w) ? i : (i - w - 1));
      const int keyR = (!h && (i <= w)) ? keyLo : keyHi;
      const float4 vp = *(const float4*)&vin[(k << 3) + (c2 ^ keyR)];
      const float4 Lp = P1[i];
      if (i <= w) a0 = cmac(cmac(a0, f2(Lp.x,Lp.y), f2(vp.x,vp.y)), f2(Lp.z,Lp.w), f2(vp.z,vp.w));
      else        a1 = cmac(cmac(a1, f2(Lp.x,Lp.y), f2(vp.x,vp.y)), f2(Lp.z,Lp.w), f2(vp.z,vp.w));
    }
    if (!h) {  // epilogue slab 9 of group A: rhi slab 7-w
      const float4 vp = *(const float4*)&vin[((7 - w) << 3) + (c2 ^ keyHi)];
      const float4 Lp = P1[8];
      a1 = cmac(cmac(a1, f2(Lp.x,Lp.y), f2(vp.x,vp.y)), f2(Lp.z,Lp.w), f2(vp.z,vp.w));
    }
    float2 vLo = h ? f2(0.f, 0.f) : a0;
    float2 vHi = h ? cadd(a0, a1) : a1;
    vLo = red8(vLo);
    vHi = red8(vHi);
    if (c == 0) wvv[h ? rhi : rlo] = h ? vHi : vLo;
  }
  __syncthreads();

  // ---- pass 2: z_j = sum_{i>=j} conj(L[i][j]) w[i]  (+ fused dot(vin,z)) ----
  {
    const int key2 = c2;
    float2 a0 = f2(0.f, 0.f), a1 = f2(0.f, 0.f);
    #pragma unroll
    for (int i = 0; i < 8; ++i) {
      int k, j;
      if (i <= w) {
        k = h ? (8 + i) : (15 - w + i);
        j = h ? rlo : rhi;
      } else {
        k = h ? (8 + i) : (i - 1);
        j = rlo;
      }
      const int u    = (k + 1) << 3;
      const int off0 = u * ((k << 2) + c2) + (k << 4) + (c2 << 1) + (j ^ key2);
      const int off1 = off0 + u + 2;
      const int i0   = (k << 3) + c2;
      const float2 La = Lc2[off0];
      const float2 Lb = Lc2[off1];
      const float4 wp = *(const float4*)&wvv[i0];
      if (i <= w) a0 = cmacc(cmacc(a0, La, f2(wp.x,wp.y)), Lb, f2(wp.z,wp.w));
      else        a1 = cmacc(cmacc(a1, La, f2(wp.x,wp.y)), Lb, f2(wp.z,wp.w));
    }
    if (!h) {  // epilogue slab 9 of group A: jlo slab 7 (rows 56+c2, 57+c2)
      const int o0 = (64 * (28 + c2)) + 112 + (c2 << 1) + (rlo ^ key2);
      const float2 La = Lc2[o0];
      const float2 Lb = Lc2[o0 + 66];
      const float4 wp = *(const float4*)&wvv[56 + c2];
      a1 = cmacc(cmacc(a1, La, f2(wp.x,wp.y)), Lb, f2(wp.z,wp.w));
    }
    float2 vJhi = h ? f2(0.f, 0.f) : a0;
    float2 vJlo = h ? cadd(a0, a1) : a1;
    vJhi = red8(vJhi);
    vJlo = red8(vJlo);
    // fused dot(vin, z): c0 lane holds z_j; partial = conj(r_j) z_j
    float2 dotp = f2(0.f, 0.f);
    if (c == 0) {
      const int jw = h ? rlo : rhi;
      const float2 zj = h ? vJlo : vJhi;
      vout[jw] = zj;
      dotp = cmacc(f2(0.f, 0.f), vin[jw], zj);
    }
    #pragma unroll
    for (int off = 32; off >= 4; off >>= 1) {
      dotp.x += __shfl_down(dotp.x, off, 64);
      dotp.y += __shfl_down(dotp.y, off, 64);
    }
    if (lane == 0) scal[w] = dotp;
  }
  __syncthreads();                                   // publishes zv + scal[0..7]
}

// LDS caps residency at 2 blocks/CU = 4 waves/EU; pin the allocator's
// occupancy target to exactly that so the VGPR budget is 128/wave (not the
// default 8-wave/64-VGPR target that spilled P1 in prior builds).
extern "C" __global__ void __launch_bounds__(TPB)
__attribute__((amdgpu_waves_per_eu(4, 4)))
cg_loss_kernel(const float* __restrict__ nre, const float* __restrict__ nim,
               const float* __restrict__ theta, const float* __restrict__ bin,
               float* __restrict__ out, float invB)
{
  __shared__ __align__(16) float2 Lc2[NPAD8R];      // 71680 B skewed+swizzled triangle
  __shared__ __align__(16) float2 Uc[128];
  __shared__ __align__(16) float2 bv[NV], rv[NV], pv[NV];
  __shared__ __align__(16) float2 zv[NV], tv[NV], wv[NV];
  __shared__ float2 scal[12];
  // total LDS = 71680 + 1024 + 6144 + 96 = 78944 B -> 2 blocks/CU

  const int t = threadIdx.x;
  const long long b = blockIdx.x;
  const int w = t >> 6, lane = t & 63;

  // ---- zero the padded triangle (pads/gaps must read as 0), init ----
  for (int p = t; p < NPAD8R; p += TPB) Lc2[p] = make_float2(0.f, 0.f);
  float2 xr = f2(0.f, 0.f), rr = f2(0.f, 0.f), pr = f2(0.f, 0.f), rz = f2(1.f, 0.f);
  if (t < NV) {
    float th = theta[b * 128 + t];
    float sn, cs;
    sincosf(th, &sn, &cs);
    Uc[t] = make_float2(cs, sn);                    // exp(i*theta)
    float bb = bin[b * 128 + t];
    bv[t] = make_float2(bb, 0.f);
    rr = make_float2(bb, 0.f);                      // r = b - A(0)
    rv[t] = rr;
  }
  __syncthreads();

  // ---- stage L into skewed+swizzled LDS; global reads fully coalesced ----
  {
    const float* nreb = nre + b * NTRI;
    const float* nimb = nim + b * NTRI;
    for (int p = t; p < NTRI; p += TPB) {
      float re = nreb[p], im = nimb[p];
      int r = (int)((sqrtf(8.f * (float)p + 1.f) - 1.f) * 0.5f + 1e-3f);
      int tr = (r * (r + 1)) >> 1;
      if (tr > p)               { tr -= r; --r; }        // tri(r-1) = tri(r) - r
      else if (tr + r + 1 <= p) { tr += r + 1; ++r; }
      Lc2[soff8(r) + ((p - tr) ^ skey(r))] = make_float2(re, im);
    }
  }
  __syncthreads();

  // ---- one-time: this lane's pass-1 L operands -> registers ----
  float4 P1[9];
  load_P1(Lc2, P1, w, lane);

  // ---- z = M r ; rz = dot(r,z) fused ; p = z ----
  precond(Lc2, P1, rv, wv, zv, scal, w, lane);
  if (t < NV) {
    rz = cadd(cadd(cadd(scal[0],scal[1]), cadd(scal[2],scal[3])),
              cadd(cadd(scal[4],scal[5]), cadd(scal[6],scal[7])));
    pr = zv[t];
    pv[t] = pr;
  }
  __syncthreads();

  #pragma unroll 1
  for (int it = 0; it < MAXIT - 1; ++it) {
    dirac<-1>(Uc, pv, tv, t);                       // t1 = D p (publishes tv)
    float2 ap = f2(0.f, 0.f);
    if (t < NV) {                                   // Ap = Ddag t1 (registers) + pAp dot
      ap = dirac_reg<+1>(Uc, tv, t);
      float2 v = cmacc(f2(0.f,0.f), pr, ap);
      #pragma unroll
      for (int off = 32; off > 0; off >>= 1) {
        v.x += __shfl_down(v.x, off, 64);
        v.y += __shfl_down(v.y, off, 64);
      }
      if ((t & 63) == 0) scal[8 + (t >> 6)] = v;
    }
    __syncthreads();                                // publishes pAp
    if (t < NV) {                                   // axpy entirely in registers
      float2 alpha = cdiv(rz, cadd(scal[8], scal[9]));
      xr = cmac(xr, alpha, pr);                     // x += alpha p
      rr = csub(rr, cmul(alpha, ap));               // r -= alpha Ap
      rv[t] = rr;
    }
    __syncthreads();                                // publishes rv
    precond(Lc2, P1, rv, wv, zv, scal, w, lane);    // z = M r ; scal[0..7] = rz2 partials
    if (t < NV) {
      float2 rz2 = cadd(cadd(cadd(scal[0],scal[1]), cadd(scal[2],scal[3])),
                        cadd(cadd(scal[4],scal[5]), cadd(scal[6],scal[7])));
      float2 beta = cdiv(rz2, rz);
      rz = rz2;
      pr = cmac(zv[t], beta, pr);                   // p = z + beta p
      pv[t] = pr;
    }
    __syncthreads();                                // publishes pv
  }

  // ---- final iteration: only x += alpha p matters ----
  dirac<-1>(Uc, pv, tv, t);
  {
    float2 ap = f2(0.f, 0.f);
    if (t < NV) {
      ap = dirac_reg<+1>(Uc, tv, t);
      float2 v = cmacc(f2(0.f,0.f), pr, ap);
      #pragma unroll
      for (int off = 32; off > 0; off >>= 1) {
        v.x += __shfl_down(v.x, off, 64);
        v.y += __shfl_down(v.y, off, 64);
      }
      if ((t & 63) == 0) scal[8 + (t >> 6)] = v;
    }
    __syncthreads();
    if (t < NV) {
      float2 alpha = cdiv(rz, cadd(scal[8], scal[9]));
      xr = cmac(xr, alpha, pr);
      rv[t] = xr;                                   // publish x (rv slot reused)
    }
    __syncthreads();
  }

  // ---- res = A x - b ; rn = ||res|| (fused into the second hop) ----
  dirac<-1>(Uc, rv, tv, t);                         // t1 = D x
  if (t < NV) {
    float2 ax = dirac_reg<+1>(Uc, tv, t);           // Ax = Ddag t1
    float2 d = csub(ax, bv[t]);
    float v = fmaf(d.x, d.x, d.y * d.y);
    #pragma unroll
    for (int off = 32; off > 0; off >>= 1) v += __shfl_down(v, off, 64);
    if ((t & 63) == 0) scal[10 + (t >> 6)].x = v;
  }
  __syncthreads();
  if (t == 0) {
    float rn = sqrtf(scal[10].x + scal[11].x);
    atomicAdd(out, rn * invB);
  }
}

extern "C" void kernel_launch(void* const* d_in, const int* in_sizes, int n_in,
                              void* d_out, int out_size, void* d_ws, size_t ws_size,
                              hipStream_t stream)
{
  const float* nre   = (const float*)d_in[0];
  const float* nim   = (const float*)d_in[1];
  const float* theta = (const float*)d_in[2];
  const float* bin   = (const float*)d_in[3];
  float* out = (float*)d_out;
  const int B = in_sizes[0] / NTRI;   // 2048

  hipMemsetAsync(out, 0, sizeof(float), stream);
  cg_loss_kernel<<<B, TPB, 0, stream>>>(nre, nim, theta, bin, out, 1.0f / (float)B);
}

// Round 10
// 999.829 us; speedup vs baseline: 1.2143x; 1.2125x over previous
//
#include <hip/hip_runtime.h>
#include <math.h>

#define NV 128         // vector length (complex) = 8*8*2
#define NTRI 8256      // lower-tri entries of 128x128
#define NPAD8R 8960    // 8-padded triangle (8704) + 2-complex skew per row (256)
#define KAP 0.276f
#define MAXIT 20
#define TPB 1024       // 16 waves; LDS ~78 KB -> 2 blocks/CU = 32 waves/CU (full occupancy)

__device__ __forceinline__ float2 f2(float x, float y){ return make_float2(x, y); }
__device__ __forceinline__ float2 cadd(float2 a, float2 b){ return make_float2(a.x+b.x, a.y+b.y); }
__device__ __forceinline__ float2 csub(float2 a, float2 b){ return make_float2(a.x-b.x, a.y-b.y); }
__device__ __forceinline__ float2 cmul(float2 a, float2 b){ return make_float2(a.x*b.x - a.y*b.y, a.x*b.y + a.y*b.x); }
__device__ __forceinline__ float2 cmulc(float2 a, float2 b){ // conj(a)*b
  return make_float2(a.x*b.x + a.y*b.y, a.x*b.y - a.y*b.x); }
__device__ __forceinline__ float2 cmac(float2 acc, float2 a, float2 b){ // acc += a*b
  acc.x = fmaf(a.x, b.x, fmaf(-a.y, b.y, acc.x));
  acc.y = fmaf(a.x, b.y, fmaf( a.y, b.x, acc.y));
  return acc; }
__device__ __forceinline__ float2 cmacc(float2 acc, float2 a, float2 b){ // acc += conj(a)*b
  acc.x = fmaf(a.x, b.x, fmaf( a.y, b.y, acc.x));
  acc.y = fmaf(a.x, b.y, fmaf(-a.y, b.x, acc.y));
  return acc; }
__device__ __forceinline__ float2 cdiv(float2 n, float2 d){
  float s = 1.0f / fmaf(d.x, d.x, d.y*d.y);
  return make_float2((n.x*d.x + n.y*d.y)*s, (n.y*d.x - n.x*d.y)*s); }

// Row r start: 8-padded triangle offset + 2-complex-per-row skew (bank spread).
__device__ __forceinline__ int soff8(int r){
  const int a = r >> 3;
  return ((((a + 1) * ((a << 2) + (r & 7)))) << 3) + (r << 1);
}
// storage swizzle key for row r: XOR on complex-index bits 1-2
__device__ __forceinline__ int skey(int r){ return ((r >> 1) & 3) << 1; }

// sum over the 16 lanes {c=0..3} x {s=0..3} of a pair group (xor 1,2,16,32)
__device__ __forceinline__ float2 red16(float2 v){
  v.x += __shfl_xor(v.x, 1);  v.y += __shfl_xor(v.y, 1);
  v.x += __shfl_xor(v.x, 2);  v.y += __shfl_xor(v.y, 2);
  v.x += __shfl_xor(v.x, 16); v.y += __shfl_xor(v.y, 16);
  v.x += __shfl_xor(v.x, 32); v.y += __shfl_xor(v.y, 32);
  return v;
}

// Wilson-Dirac hop. EF = coefficient sign of G on the FORWARD hop:
//   D : fwd (I - G), bwd (I + G) -> EF=-1 ; Ddag : EF=+1
template<int EF>
__device__ __forceinline__ float2 dirac_reg(const float2* __restrict__ U,
                                            const float2* __restrict__ vin, int t)
{
  const int s = t & 1, site = t >> 1;
  const int yi = site & 7, xi = site >> 3;
  const int xp = (xi+1)&7, xm = (xi-1)&7, yp = (yi+1)&7, ym = (yi-1)&7;
  float2 acc;
  {
    const int bf = (xp<<4) + (yi<<1);
    float2 fs = vin[bf + s], fo = vin[bf + (s^1)];
    float2 cf = (EF > 0) ? cadd(fs, fo) : csub(fs, fo);
    acc = cmul(U[(xi<<3)+yi], cf);
    const int bb = (xm<<4) + (yi<<1);
    float2 bs = vin[bb + s], bo = vin[bb + (s^1)];
    float2 cb = (EF > 0) ? csub(bs, bo) : cadd(bs, bo);
    acc = cadd(acc, cmulc(U[(xm<<3)+yi], cb));
  }
  {
    const float tg = s ? 1.0f : -1.0f;
    const float gf = (float)EF * tg;
    const int bf = (xi<<4) + (yp<<1);
    float2 fs = vin[bf + s], fo = vin[bf + (s^1)];
    float2 cf = make_float2(fmaf(-gf, fo.y, fs.x), fmaf(gf, fo.x, fs.y));
    acc = cadd(acc, cmul(U[64 + (xi<<3)+yi], cf));
    const float gb = -gf;
    const int bb = (xi<<4) + (ym<<1);
    float2 bs = vin[bb + s], bo = vin[bb + (s^1)];
    float2 cb = make_float2(fmaf(-gb, bo.y, bs.x), fmaf(gb, bo.x, bs.y));
    acc = cadd(acc, cmulc(U[64 + (xi<<3)+ym], cb));
  }
  float2 v0 = vin[t];
  return make_float2(fmaf(-KAP, acc.x, v0.x), fmaf(-KAP, acc.y, v0.y));
}

template<int EF>
__device__ __forceinline__ void dirac(const float2* __restrict__ U,
                                      const float2* __restrict__ vin,
                                      float2* __restrict__ vout, int t)
{
  if (t < NV) vout[t] = dirac_reg<EF>(U, vin, t);
  __syncthreads();
}

// 16-wave z = L^H (L v). Each 4-lane c-group belongs to pair (rlo, 127-rlo);
// every pair totals exactly 17 eight-wide slabs in BOTH passes, split over
// 16 lanes (4c x 4s): depth 4 + epilogue(s==0). In-wave red16 reduction,
// single wvv/zv buffers, dot(vin,z) fused into pass 2 (scal[w] partials).
// Addressing formulas identical to the round-3-verified kernel.
__device__ __forceinline__ void precond16(const float2* __restrict__ Lc2,
                                          const float2* __restrict__ vin,
                                          float2* __restrict__ wvv,
                                          float2* __restrict__ vout,
                                          float2* __restrict__ scal,
                                          int w, int lane)
{
  const int c  = lane & 3;
  const int pq = (lane >> 2) & 3;      // pair within wave
  const int s  = lane >> 4;            // slab-phase subgroup 0..3
  const int c2 = c << 1;
  const int rlo = (w << 2) + pq;       // 0..63 (4w..4w+3 never crosses an 8-block)
  const int rhi = 127 - rlo;
  const int w2  = rlo >> 3;            // wave-uniform
  const int nlo = w2 + 1;              // rlo slab count; rhi count = 16-w2
  const int bLo = soff8(rlo), bHi = soff8(rhi);
  const int keyLo = skey(rlo), keyHi = skey(rhi);

  // ---- pass 1: w_r = sum_{j<=r} L[r][j] v[j] ----
  // element list e=0..16: e<nlo -> (rlo, slab e); else (rhi, slab e-nlo)
  {
    float2 a0 = f2(0.f,0.f), a1 = f2(0.f,0.f);
    #pragma unroll
    for (int ii = 0; ii < 4; ++ii) {
      const int e    = (ii << 2) + s;
      const bool lo  = (e < nlo);
      const int k    = lo ? e : (e - nlo);
      const int base = lo ? bLo : bHi;
      const int key  = lo ? keyLo : keyHi;
      const float4 Lp = *(const float4*)&Lc2[base + (k << 3) + c2];
      const float4 vp = *(const float4*)&vin[(k << 3) + (c2 ^ key)];
      if (lo) a0 = cmac(cmac(a0, f2(Lp.x,Lp.y), f2(vp.x,vp.y)), f2(Lp.z,Lp.w), f2(vp.z,vp.w));
      else    a1 = cmac(cmac(a1, f2(Lp.x,Lp.y), f2(vp.x,vp.y)), f2(Lp.z,Lp.w), f2(vp.z,vp.w));
    }
    if (s == 0) {                      // e = 16: always rhi slab 16-nlo = 15-w2
      const int k = 16 - nlo;
      const float4 Lp = *(const float4*)&Lc2[bHi + (k << 3) + c2];
      const float4 vp = *(const float4*)&vin[(k << 3) + (c2 ^ keyHi)];
      a1 = cmac(cmac(a1, f2(Lp.x,Lp.y), f2(vp.x,vp.y)), f2(Lp.z,Lp.w), f2(vp.z,vp.w));
    }
    float2 vLo = red16(a0);
    float2 vHi = red16(a1);
    if (c == 0 && s == 0) wvv[rlo] = vLo;
    if (c == 0 && s == 1) wvv[rhi] = vHi;
  }
  __syncthreads();

  // ---- pass 2: z_j = sum_{i>=j} conj(L[i][j]) w[i]  (+ fused dot(vin,z)) ----
  // element list e=0..16: e<nlo -> (col rhi, slab 15-w2+e); else (col rlo, slab e-1)
  {
    float2 a0 = f2(0.f,0.f), a1 = f2(0.f,0.f);
    #pragma unroll
    for (int ii = 0; ii < 4; ++ii) {
      const int e   = (ii << 2) + s;
      const bool hi = (e < nlo);
      const int k = hi ? (15 - w2 + e) : (e - 1);
      const int j = hi ? rhi : rlo;
      const int u    = (k + 1) << 3;
      const int off0 = u * ((k << 2) + c2) + (k << 4) + (c2 << 1) + (j ^ c2);
      const float2 La = Lc2[off0];
      const float2 Lb = Lc2[off0 + u + 2];
      const float4 wp = *(const float4*)&wvv[(k << 3) + c2];
      if (hi) a0 = cmacc(cmacc(a0, La, f2(wp.x,wp.y)), Lb, f2(wp.z,wp.w));
      else    a1 = cmacc(cmacc(a1, La, f2(wp.x,wp.y)), Lb, f2(wp.z,wp.w));
    }
    if (s == 0) {                      // e = 16: (col rlo, slab 15)
      const int off0 = 128 * (60 + c2) + 240 + (c2 << 1) + (rlo ^ c2);
      const float2 La = Lc2[off0];
      const float2 Lb = Lc2[off0 + 130];
      const float4 wp = *(const float4*)&wvv[120 + c2];
      a1 = cmacc(cmacc(a1, La, f2(wp.x,wp.y)), Lb, f2(wp.z,wp.w));
    }
    float2 vJhi = red16(a0);
    float2 vJlo = red16(a1);
    float2 dotp = f2(0.f,0.f);
    if (c == 0 && s == 0) { vout[rhi] = vJhi; dotp = cmacc(f2(0.f,0.f), vin[rhi], vJhi); }
    if (c == 0 && s == 1) { vout[rlo] = vJlo; dotp = cmacc(f2(0.f,0.f), vin[rlo], vJlo); }
    // nonzero at lanes {0,4,8,12,16,20,24,28}: xor 4,8,16 gathers to lane 0
    dotp.x += __shfl_xor(dotp.x, 4);  dotp.y += __shfl_xor(dotp.y, 4);
    dotp.x += __shfl_xor(dotp.x, 8);  dotp.y += __shfl_xor(dotp.y, 8);
    dotp.x += __shfl_xor(dotp.x, 16); dotp.y += __shfl_xor(dotp.y, 16);
    if (lane == 0) scal[w] = dotp;
  }
  __syncthreads();                                   // publishes zv + scal[0..15]
}

__device__ __forceinline__ float2 sum16(const float2* __restrict__ scal)
{
  float2 r = scal[0];
  #pragma unroll
  for (int i = 1; i < 16; ++i) r = cadd(r, scal[i]);
  return r;
}

extern "C" __global__ void __launch_bounds__(TPB, 8)
cg_loss_kernel(const float* __restrict__ nre, const float* __restrict__ nim,
               const float* __restrict__ theta, const float* __restrict__ bin,
               float* __restrict__ out, float invB)
{
  __shared__ __align__(16) float2 Lc2[NPAD8R];      // 71680 B skewed+swizzled triangle
  __shared__ __align__(16) float2 Uc[128];
  __shared__ __align__(16) float2 rv[NV], pv[NV], tv[NV], wv[NV], zv[NV];
  __shared__ float2 scal[20];
  // total LDS = 71680 + 1024 + 5120 + 160 = 77984 B -> 2 blocks/CU (156 KB), 32 waves/CU

  const int t = threadIdx.x;
  const long long b = blockIdx.x;
  const int w = t >> 6, lane = t & 63;

  // ---- zero the padded triangle (pads/gaps must read as 0), init ----
  for (int p = t; p < NPAD8R; p += TPB) Lc2[p] = make_float2(0.f, 0.f);
  float2 xr = f2(0.f, 0.f), rr = f2(0.f, 0.f), pr = f2(0.f, 0.f), rz = f2(1.f, 0.f);
  if (t < NV) {
    float th = theta[b * 128 + t];
    float sn, cs;
    sincosf(th, &sn, &cs);
    Uc[t] = make_float2(cs, sn);                    // exp(i*theta)
    float bb = bin[b * 128 + t];
    rr = make_float2(bb, 0.f);                      // r = b - A(0)
    rv[t] = rr;
  }
  __syncthreads();

  // ---- stage L into skewed+swizzled LDS; global reads fully coalesced ----
  {
    const float* nreb = nre + b * NTRI;
    const float* nimb = nim + b * NTRI;
    for (int p = t; p < NTRI; p += TPB) {
      float re = nreb[p], im = nimb[p];
      int r = (int)((sqrtf(8.f * (float)p + 1.f) - 1.f) * 0.5f + 1e-3f);
      int tr = (r * (r + 1)) >> 1;
      if (tr > p)               { tr -= r; --r; }        // tri(r-1) = tri(r) - r
      else if (tr + r + 1 <= p) { tr += r + 1; ++r; }
      Lc2[soff8(r) + ((p - tr) ^ skey(r))] = make_float2(re, im);
    }
  }
  __syncthreads();

  // ---- z = M r ; rz = dot(r,z) fused ; p = z ----
  precond16(Lc2, rv, wv, zv, scal, w, lane);
  if (t < NV) {
    rz = sum16(scal);
    pr = zv[t];
    pv[t] = pr;
  }
  __syncthreads();

  #pragma unroll 1
  for (int it = 0; it < MAXIT - 1; ++it) {
    dirac<-1>(Uc, pv, tv, t);                       // t1 = D p (publishes tv)
    float2 ap = f2(0.f, 0.f);
    if (t < NV) {                                   // Ap = Ddag t1 (registers) + pAp dot
      ap = dirac_reg<+1>(Uc, tv, t);
      float2 v = cmacc(f2(0.f,0.f), pr, ap);
      #pragma unroll
      for (int off = 32; off > 0; off >>= 1) {
        v.x += __shfl_down(v.x, off, 64);
        v.y += __shfl_down(v.y, off, 64);
      }
      if ((t & 63) == 0) scal[16 + (t >> 6)] = v;
    }
    __syncthreads();                                // publishes pAp
    if (t < NV) {                                   // axpy in registers
      float2 alpha = cdiv(rz, cadd(scal[16], scal[17]));
      xr = cmac(xr, alpha, pr);                     // x += alpha p
      rr = csub(rr, cmul(alpha, ap));               // r -= alpha Ap
      rv[t] = rr;
    }
    __syncthreads();                                // publishes rv
    precond16(Lc2, rv, wv, zv, scal, w, lane);      // z = M r ; scal[0..15] = rz2 partials
    if (t < NV) {
      float2 rz2 = sum16(scal);
      float2 beta = cdiv(rz2, rz);
      rz = rz2;
      pr = cmac(zv[t], beta, pr);                   // p = z + beta p
      pv[t] = pr;
    }
    __syncthreads();                                // publishes pv
  }

  // ---- final iteration: only x += alpha p matters ----
  dirac<-1>(Uc, pv, tv, t);
  {
    float2 ap = f2(0.f, 0.f);
    if (t < NV) {
      ap = dirac_reg<+1>(Uc, tv, t);
      float2 v = cmacc(f2(0.f,0.f), pr, ap);
      #pragma unroll
      for (int off = 32; off > 0; off >>= 1) {
        v.x += __shfl_down(v.x, off, 64);
        v.y += __shfl_down(v.y, off, 64);
      }
      if ((t & 63) == 0) scal[16 + (t >> 6)] = v;
    }
    __syncthreads();
    if (t < NV) {
      float2 alpha = cdiv(rz, cadd(scal[16], scal[17]));
      xr = cmac(xr, alpha, pr);
      rv[t] = xr;                                   // publish x (rv slot reused)
    }
    __syncthreads();
  }

  // ---- res = A x - b ; rn = ||res|| ----
  dirac<-1>(Uc, rv, tv, t);                         // t1 = D x
  if (t < NV) {
    float2 ax = dirac_reg<+1>(Uc, tv, t);           // Ax = Ddag t1
    float bb = bin[b * 128 + t];
    float dx = ax.x - bb, dy = ax.y;
    float v = fmaf(dx, dx, dy * dy);
    #pragma unroll
    for (int off = 32; off > 0; off >>= 1) v += __shfl_down(v, off, 64);
    if ((t & 63) == 0) scal[18 + (t >> 6)].x = v;
  }
  __syncthreads();
  if (t == 0) {
    float rn = sqrtf(scal[18].x + scal[19].x);
    atomicAdd(out, rn * invB);
  }
}

extern "C" void kernel_launch(void* const* d_in, const int* in_sizes, int n_in,
                              void* d_out, int out_size, void* d_ws, size_t ws_size,
                              hipStream_t stream)
{
  const float* nre   = (const float*)d_in[0];
  const float* nim   = (const float*)d_in[1];
  const float* theta = (const float*)d_in[2];
  const float* bin   = (const float*)d_in[3];
  float* out = (float*)d_out;
  const int B = in_sizes[0] / NTRI;   // 2048

  hipMemsetAsync(out, 0, sizeof(float), stream);
  cg_loss_kernel<<<B, TPB, 0, stream>>>(nre, nim, theta, bin, out, 1.0f / (float)B);
}